// Round 3
// baseline (1362.104 us; speedup 1.0000x reference)
//
#include <hip/hip_runtime.h>
#include <hip/hip_bf16.h>

// Swin stage: B=64 H=W=56 D=128 WS=7 NH=4 L=2 HID=512, downsample 4D->2D.
// Strategy: bf16 MFMA GEMMs (16x16x32), vector-f32 window attention (round 1),
// LN pre-passes producing bf16 activation matrices, epilogue-fused residuals.

typedef short bf16x8 __attribute__((ext_vector_type(8)));
typedef float f32x4 __attribute__((ext_vector_type(4)));
typedef unsigned short u16;
typedef unsigned int u32;

#define MTOK 200704   // B*H*W tokens
#define DSTOK 50176   // B*28*28

__device__ __forceinline__ u16 f2b(float f){
  u32 u = __float_as_uint(f);
  u += 0x7fffu + ((u >> 16) & 1u);
  return (u16)(u >> 16);
}
__device__ __forceinline__ float blo(u32 u){ return __uint_as_float(u << 16); }
__device__ __forceinline__ float bhi(u32 u){ return __uint_as_float(u & 0xffff0000u); }

__device__ __forceinline__ float gelu_tanh(float v){
  float u = 0.7978845608028654f * (v + 0.044715f * v * v * v);
  u = fminf(u, 10.f);
  float e = __expf(2.f * u);
  float t = (e - 1.f) / (e + 1.f);
  return 0.5f * v * (1.f + t);
}

// ---------------- weight transpose + bf16 cast: src[K][N] f32 -> dst[N][K] bf16
__global__ void transpose_cvt(const float* __restrict__ src, u16* __restrict__ dst,
                              int K, int N){
  int e = blockIdx.x * 256 + threadIdx.x;
  if (e >= K * N) return;
  int k = e / N, n = e - k * N;
  dst[n * K + k] = f2b(src[e]);
}

// ---------------- LayerNorm pass -> bf16 rows
// MODE 0: window order, no shift; MODE 1: window order, shift +3; MODE 2: linear
template<int MODE>
__global__ __launch_bounds__(256) void ln_kernel(const float* __restrict__ src,
    const float* __restrict__ gw, const float* __restrict__ bw,
    u16* __restrict__ dst)
{
  int wv = threadIdx.x >> 6, lane = threadIdx.x & 63;
  int t = blockIdx.x * 4 + wv;
  long soff;
  if (MODE == 2) {
    soff = (long)t * 128;
  } else {
    int n = t % 49; int tq = t / 49; int gg = tq & 63; int b_ = tq >> 6;
    int r = n / 7, c = n - 7 * r;
    int h = (gg >> 3) * 7 + r, w = (gg & 7) * 7 + c;
    if (MODE == 1) { h += 3; if (h >= 56) h -= 56; w += 3; if (w >= 56) w -= 56; }
    soff = ((long)((b_ * 56 + h) * 56 + w)) * 128;
  }
  float2 v = *(const float2*)(src + soff + lane * 2);
  float s = v.x + v.y, s2 = v.x * v.x + v.y * v.y;
  #pragma unroll
  for (int o = 32; o; o >>= 1) { s += __shfl_xor(s, o); s2 += __shfl_xor(s2, o); }
  float mean = s * 0.0078125f;
  float var  = s2 * 0.0078125f - mean * mean;
  float rstd = rsqrtf(var + 1e-5f);
  int c0 = lane * 2;
  ushort2 o2;
  o2.x = f2b((v.x - mean) * rstd * gw[c0]   + bw[c0]);
  o2.y = f2b((v.y - mean) * rstd * gw[c0+1] + bw[c0+1]);
  *(ushort2*)(dst + (long)t * 128 + c0) = o2;
}

// ---------------- downsample gather + LN(512) -> bf16 rows [DSTOK][512]
__global__ __launch_bounds__(256) void ds_ln_kernel(const float* __restrict__ x,
    const float* __restrict__ gw, const float* __restrict__ bw,
    u16* __restrict__ dst)
{
  int wv = threadIdx.x >> 6, lane = threadIdx.x & 63;
  int t = blockIdx.x * 4 + wv;                  // 0..50175
  int j = t % 28; int tq = t / 28; int i = tq % 28; int b_ = tq / 28;
  int e0 = lane * 8;
  int p = e0 >> 8, q = (e0 >> 7) & 1, d = e0 & 127;
  const float* src = x + ((long)((b_ * 56 + 2*i + p) * 56 + 2*j + q)) * 128 + d;
  float4 a  = *(const float4*)src;
  float4 b4 = *(const float4*)(src + 4);
  float vs[8] = {a.x, a.y, a.z, a.w, b4.x, b4.y, b4.z, b4.w};
  float s = 0.f, s2 = 0.f;
  #pragma unroll
  for (int u = 0; u < 8; u++) { s += vs[u]; s2 += vs[u] * vs[u]; }
  #pragma unroll
  for (int o = 32; o; o >>= 1) { s += __shfl_xor(s, o); s2 += __shfl_xor(s2, o); }
  float mean = s * (1.f / 512.f);
  float var  = s2 * (1.f / 512.f) - mean * mean;
  float rstd = rsqrtf(var + 1e-5f);
  u16 ov[8];
  #pragma unroll
  for (int u = 0; u < 8; u++) ov[u] = f2b((vs[u] - mean) * rstd * gw[e0+u] + bw[e0+u]);
  uint4 o4;
  o4.x = (u32)ov[0] | ((u32)ov[1] << 16);
  o4.y = (u32)ov[2] | ((u32)ov[3] << 16);
  o4.z = (u32)ov[4] | ((u32)ov[5] << 16);
  o4.w = (u32)ov[6] | ((u32)ov[7] << 16);
  *(uint4*)(dst + (long)t * 512 + e0) = o4;
}

// ---------------- window attention, vector f32 (round-1 baseline)
// block = window; wave = head; lane = query row (lane<49 active)
template<int MASKED>
__global__ __launch_bounds__(256) void attn_kernel(const u16* __restrict__ qkv,
                                                   u16* __restrict__ obuf)
{
  __shared__ u16 kls[4][49][32];
  __shared__ u16 vls[4][49][32];
  __shared__ float sls[4][49][51];   // pad 51 to spread banks
  int wi = blockIdx.x;
  int g_ = wi & 63;
  long t0 = (long)wi * 49;
  int h = threadIdx.x >> 6, lane = threadIdx.x & 63;
  float qreg[32];
  if (lane < 49) {
    const u16* qp = qkv + (t0 + lane) * 384 + h * 32;
    const u16* kp = qp + 128;
    const u16* vp = qp + 256;
    #pragma unroll
    for (int j = 0; j < 4; j++) {
      *(uint4*)&kls[h][lane][j*8] = *(const uint4*)(kp + j*8);
      *(uint4*)&vls[h][lane][j*8] = *(const uint4*)(vp + j*8);
    }
    #pragma unroll
    for (int j = 0; j < 16; j++) {
      u32 u = *(const u32*)(qp + j*2);
      qreg[2*j]   = blo(u);
      qreg[2*j+1] = bhi(u);
    }
  }
  __syncthreads();
  if (lane >= 49) return;

  int g1b = (g_ >> 3) * 7, g2b = (g_ & 7) * 7;
  int ridn = 0;
  if (MASKED) {
    int rn = lane / 7, cn = lane - 7 * rn;
    int hn = g1b + rn, wn = g2b + cn;
    ridn = (hn < 49 ? 0 : (hn < 53 ? 1 : 2)) * 3 + (wn < 49 ? 0 : (wn < 53 ? 1 : 2));
  }
  float smax = -3.0e38f;
  for (int m = 0; m < 49; m++) {
    const u32* kp32 = (const u32*)&kls[h][m][0];
    float s = 0.f;
    #pragma unroll
    for (int j = 0; j < 16; j++) {
      u32 u = kp32[j];
      s = fmaf(qreg[2*j],   blo(u), s);
      s = fmaf(qreg[2*j+1], bhi(u), s);
    }
    s *= 0.17677669529663687f;   // 1/sqrt(32)
    if (MASKED) {
      int rm = m / 7, cm = m - 7 * rm;
      int hm = g1b + rm, wm = g2b + cm;
      int ridm = (hm < 49 ? 0 : (hm < 53 ? 1 : 2)) * 3 + (wm < 49 ? 0 : (wm < 53 ? 1 : 2));
      if (ridm != ridn) s -= 100.f;
    }
    smax = fmaxf(smax, s);
    sls[h][lane][m] = s;
  }
  float sum = 0.f;
  for (int m = 0; m < 49; m++) {
    float e = __expf(sls[h][lane][m] - smax);
    sum += e;
    sls[h][lane][m] = e;
  }
  float rs = 1.f / sum;
  float o[32];
  #pragma unroll
  for (int d = 0; d < 32; d++) o[d] = 0.f;
  for (int m = 0; m < 49; m++) {
    float p = sls[h][lane][m];
    const u32* vp32 = (const u32*)&vls[h][m][0];
    #pragma unroll
    for (int j = 0; j < 16; j++) {
      u32 u = vp32[j];
      o[2*j]   = fmaf(p, blo(u), o[2*j]);
      o[2*j+1] = fmaf(p, bhi(u), o[2*j+1]);
    }
  }
  u16* op = obuf + (t0 + lane) * 128 + h * 32;
  #pragma unroll
  for (int j = 0; j < 16; j++) {
    ushort2 w2;
    w2.x = f2b(o[2*j]   * rs);
    w2.y = f2b(o[2*j+1] * rs);
    *(ushort2*)(op + 2*j) = w2;
  }
}

// ---------------- MFMA GEMM: C[M,Ntot] = A[M,K](bf16) * Bt[Ntot,K]^T (bf16)
// 128x128 tile, 4 waves, BK=64, LDS pad +8 (conflict-free frag reads).
// EPI: 0 bias->bf16 | 1 bias+gelu->bf16 | 2 bias+residual f32 scatter (window->x)
//      3 bias, outf += (linear)         | 4 plain f32 store
template<int K, int EPI>
__global__ __launch_bounds__(256) void gemm_kernel(
    const u16* __restrict__ A, const u16* __restrict__ Bt,
    const float* __restrict__ bias, int Ntot,
    u16* __restrict__ outb, float* __restrict__ outf,
    const float* __restrict__ resbase, int shift)
{
  __shared__ u16 As[128][72];
  __shared__ u16 Bs[128][72];
  const int tid = threadIdx.x;
  const int row0 = blockIdx.x * 128, col0 = blockIdx.y * 128;
  const int wv = tid >> 6, lane = tid & 63;
  const int m_off = (wv >> 1) * 64, n_off = (wv & 1) * 64;
  const int lr = lane & 15, lk = (lane >> 4) * 8;

  f32x4 acc[4][4];
  const f32x4 zero4 = {0.f, 0.f, 0.f, 0.f};
  #pragma unroll
  for (int a1 = 0; a1 < 4; a1++)
    #pragma unroll
    for (int a2 = 0; a2 < 4; a2++) acc[a1][a2] = zero4;

  for (int k0 = 0; k0 < K; k0 += 64) {
    __syncthreads();
    #pragma unroll
    for (int j = 0; j < 4; j++) {
      int ch = tid + 256 * j;           // 1024 chunks of 16B
      int r = ch >> 3, cc = ch & 7;
      *(uint4*)(&As[r][cc*8]) = *(const uint4*)(A  + (long)(row0 + r) * K + k0 + cc*8);
      *(uint4*)(&Bs[r][cc*8]) = *(const uint4*)(Bt + (long)(col0 + r) * K + k0 + cc*8);
    }
    __syncthreads();
    #pragma unroll
    for (int kk = 0; kk < 64; kk += 32) {
      bf16x8 af[4], bfr[4];
      #pragma unroll
      for (int mi = 0; mi < 4; mi++)
        af[mi] = *(const bf16x8*)(&As[m_off + mi*16 + lr][kk + lk]);
      #pragma unroll
      for (int ni = 0; ni < 4; ni++)
        bfr[ni] = *(const bf16x8*)(&Bs[n_off + ni*16 + lr][kk + lk]);
      #pragma unroll
      for (int mi = 0; mi < 4; mi++)
        #pragma unroll
        for (int ni = 0; ni < 4; ni++)
          acc[mi][ni] = __builtin_amdgcn_mfma_f32_16x16x32_bf16(
              af[mi], bfr[ni], acc[mi][ni], 0, 0, 0);
    }
  }

  #pragma unroll
  for (int mi = 0; mi < 4; mi++) {
    #pragma unroll
    for (int j = 0; j < 4; j++) {
      int grow = row0 + m_off + mi*16 + (lane >> 4) * 4 + j;
      long obase = 0;
      if (EPI == 2) {
        int n = grow % 49; int tq = grow / 49; int gg = tq & 63; int b_ = tq >> 6;
        int r = n / 7, c = n - 7 * r;
        int hh = (gg >> 3) * 7 + r, ww = (gg & 7) * 7 + c;
        if (shift) { hh += 3; if (hh >= 56) hh -= 56; ww += 3; if (ww >= 56) ww -= 56; }
        obase = ((long)((b_ * 56 + hh) * 56 + ww)) * 128;
      }
      #pragma unroll
      for (int ni = 0; ni < 4; ni++) {
        int gcol = col0 + n_off + ni*16 + lr;
        float v = acc[mi][ni][j];
        if (EPI == 0) {
          v += bias[gcol];
          outb[(long)grow * Ntot + gcol] = f2b(v);
        } else if (EPI == 1) {
          v = gelu_tanh(v + bias[gcol]);
          outb[(long)grow * Ntot + gcol] = f2b(v);
        } else if (EPI == 2) {
          v += bias[gcol];
          outf[obase + gcol] = resbase[obase + gcol] + v;
        } else if (EPI == 3) {
          v += bias[gcol];
          outf[(long)grow * 128 + gcol] += v;
        } else {
          outf[(long)grow * Ntot + gcol] = v;
        }
      }
    }
  }
}

extern "C" void kernel_launch(void* const* d_in, const int* in_sizes, int n_in,
                              void* d_out, int out_size, void* d_ws, size_t ws_size,
                              hipStream_t stream)
{
  const float* x_in   = (const float*)d_in[0];
  const float* ln1_g  = (const float*)d_in[1];
  const float* ln1_b  = (const float*)d_in[2];
  const float* qkv_w  = (const float*)d_in[3];
  const float* qkv_b  = (const float*)d_in[4];
  const float* proj_w = (const float*)d_in[5];
  const float* proj_b = (const float*)d_in[6];
  const float* ln2_g  = (const float*)d_in[7];
  const float* ln2_b  = (const float*)d_in[8];
  const float* w1     = (const float*)d_in[9];
  const float* b1     = (const float*)d_in[10];
  const float* w2     = (const float*)d_in[11];
  const float* b2     = (const float*)d_in[12];
  const float* dsg    = (const float*)d_in[13];
  const float* dsb    = (const float*)d_in[14];
  const float* dsw    = (const float*)d_in[15];

  // workspace carve (~360 MB). buf_o aliases buf_h (never live simultaneously:
  // LN1 out (buf_h) is consumed by the QKV GEMM before attention writes buf_o).
  float* x_ws   = (float*)d_ws;                          // [MTOK][128] f32
  u16* buf_h    = (u16*)(x_ws + (long)MTOK * 128);       // [MTOK][128] bf16 (LN out / attn out / ds rows)
  u16* buf_o    = buf_h;                                 // alias
  u16* buf_big  = buf_h + (long)MTOK * 128;              // [MTOK][512] bf16 (qkv / mlp hidden)
  u16* wts      = buf_big + (long)MTOK * 512;
  u16* qkv_wt   = wts;                                   // [L][384][128]
  u16* proj_wt  = qkv_wt  + 2 * 49152;                   // [L][128][128]
  u16* w1t      = proj_wt + 2 * 16384;                   // [L][512][128]
  u16* w2t      = w1t     + 2 * 65536;                   // [L][128][512]
  u16* ds_wt    = w2t     + 2 * 65536;                   // [256][512]

  for (int i = 0; i < 2; i++) {
    transpose_cvt<<<(49152+255)/256, 256, 0, stream>>>(qkv_w  + i*49152, qkv_wt  + i*49152, 128, 384);
    transpose_cvt<<<(16384+255)/256, 256, 0, stream>>>(proj_w + i*16384, proj_wt + i*16384, 128, 128);
    transpose_cvt<<<(65536+255)/256, 256, 0, stream>>>(w1     + i*65536, w1t     + i*65536, 128, 512);
    transpose_cvt<<<(65536+255)/256, 256, 0, stream>>>(w2     + i*65536, w2t     + i*65536, 512, 128);
  }
  transpose_cvt<<<(131072+255)/256, 256, 0, stream>>>(dsw, ds_wt, 512, 256);

  for (int i = 0; i < 2; i++) {
    // LN1 (window order; layer1 = shifted gather)
    if (i == 0) ln_kernel<0><<<MTOK/4, 256, 0, stream>>>(x_in, ln1_g,       ln1_b,       buf_h);
    else        ln_kernel<1><<<MTOK/4, 256, 0, stream>>>(x_ws, ln1_g + 128, ln1_b + 128, buf_h);
    // QKV
    gemm_kernel<128,0><<<dim3(MTOK/128, 3), 256, 0, stream>>>(
        buf_h, qkv_wt + i*49152, qkv_b + i*384, 384, buf_big, nullptr, nullptr, 0);
    // attention
    if (i == 0) attn_kernel<0><<<4096, 256, 0, stream>>>(buf_big, buf_o);
    else        attn_kernel<1><<<4096, 256, 0, stream>>>(buf_big, buf_o);
    // proj + residual scatter into x_ws
    gemm_kernel<128,2><<<dim3(MTOK/128, 1), 256, 0, stream>>>(
        buf_o, proj_wt + i*16384, proj_b + i*128, 128, nullptr, x_ws,
        (i == 0 ? x_in : (const float*)x_ws), i);
    // LN2 (linear)
    ln_kernel<2><<<MTOK/4, 256, 0, stream>>>(x_ws, ln2_g + i*128, ln2_b + i*128, buf_h);
    // MLP
    gemm_kernel<128,1><<<dim3(MTOK/128, 4), 256, 0, stream>>>(
        buf_h, w1t + i*65536, b1 + i*512, 512, buf_big, nullptr, nullptr, 0);
    gemm_kernel<512,3><<<dim3(MTOK/128, 1), 256, 0, stream>>>(
        buf_big, w2t + i*65536, b2 + i*128, 128, nullptr, x_ws, x_ws, 0);
  }

  // downsample
  ds_ln_kernel<<<DSTOK/4, 256, 0, stream>>>(x_ws, dsg, dsb, buf_h);
  gemm_kernel<512,4><<<dim3(DSTOK/128, 2), 256, 0, stream>>>(
      buf_h, ds_wt, nullptr, 256, nullptr, (float*)d_out, nullptr, 0);
}

// Round 4
// 1111.132 us; speedup vs baseline: 1.2259x; 1.2259x over previous
//
#include <hip/hip_runtime.h>
#include <hip/hip_bf16.h>

// Swin stage: B=64 H=W=56 D=128 WS=7 NH=4 L=2 HID=512, downsample 4D->2D.
// Round 4: MFMA window attention (head_dim=32 == K of mfma_16x16x32_bf16).
// Q/K/V fragments loaded straight from global (zero reuse -> no staging);
// P routed through LDS [64][72] (16B-aligned rows, 2-way-conflict-free).

typedef short bf16x8 __attribute__((ext_vector_type(8)));
typedef float f32x4 __attribute__((ext_vector_type(4)));
typedef unsigned short u16;
typedef unsigned int u32;

#define MTOK 200704   // B*H*W tokens
#define DSTOK 50176   // B*28*28

__device__ __forceinline__ u16 f2b(float f){
  u32 u = __float_as_uint(f);
  u += 0x7fffu + ((u >> 16) & 1u);
  return (u16)(u >> 16);
}
__device__ __forceinline__ float blo(u32 u){ return __uint_as_float(u << 16); }
__device__ __forceinline__ float bhi(u32 u){ return __uint_as_float(u & 0xffff0000u); }

__device__ __forceinline__ float gelu_tanh(float v){
  float u = 0.7978845608028654f * (v + 0.044715f * v * v * v);
  u = fminf(u, 10.f);
  float e = __expf(2.f * u);
  float t = (e - 1.f) / (e + 1.f);
  return 0.5f * v * (1.f + t);
}

// ---------------- weight transpose + bf16 cast: src[K][N] f32 -> dst[N][K] bf16
__global__ void transpose_cvt(const float* __restrict__ src, u16* __restrict__ dst,
                              int K, int N){
  int e = blockIdx.x * 256 + threadIdx.x;
  if (e >= K * N) return;
  int k = e / N, n = e - k * N;
  dst[n * K + k] = f2b(src[e]);
}

// ---------------- LayerNorm pass -> bf16 rows
// MODE 0: window order, no shift; MODE 1: window order, shift +3; MODE 2: linear
template<int MODE>
__global__ __launch_bounds__(256) void ln_kernel(const float* __restrict__ src,
    const float* __restrict__ gw, const float* __restrict__ bw,
    u16* __restrict__ dst)
{
  int wv = threadIdx.x >> 6, lane = threadIdx.x & 63;
  int t = blockIdx.x * 4 + wv;
  long soff;
  if (MODE == 2) {
    soff = (long)t * 128;
  } else {
    int n = t % 49; int tq = t / 49; int gg = tq & 63; int b_ = tq >> 6;
    int r = n / 7, c = n - 7 * r;
    int h = (gg >> 3) * 7 + r, w = (gg & 7) * 7 + c;
    if (MODE == 1) { h += 3; if (h >= 56) h -= 56; w += 3; if (w >= 56) w -= 56; }
    soff = ((long)((b_ * 56 + h) * 56 + w)) * 128;
  }
  float2 v = *(const float2*)(src + soff + lane * 2);
  float s = v.x + v.y, s2 = v.x * v.x + v.y * v.y;
  #pragma unroll
  for (int o = 32; o; o >>= 1) { s += __shfl_xor(s, o); s2 += __shfl_xor(s2, o); }
  float mean = s * 0.0078125f;
  float var  = s2 * 0.0078125f - mean * mean;
  float rstd = rsqrtf(var + 1e-5f);
  int c0 = lane * 2;
  ushort2 o2;
  o2.x = f2b((v.x - mean) * rstd * gw[c0]   + bw[c0]);
  o2.y = f2b((v.y - mean) * rstd * gw[c0+1] + bw[c0+1]);
  *(ushort2*)(dst + (long)t * 128 + c0) = o2;
}

// ---------------- downsample gather + LN(512) -> bf16 rows [DSTOK][512]
__global__ __launch_bounds__(256) void ds_ln_kernel(const float* __restrict__ x,
    const float* __restrict__ gw, const float* __restrict__ bw,
    u16* __restrict__ dst)
{
  int wv = threadIdx.x >> 6, lane = threadIdx.x & 63;
  int t = blockIdx.x * 4 + wv;                  // 0..50175
  int j = t % 28; int tq = t / 28; int i = tq % 28; int b_ = tq / 28;
  int e0 = lane * 8;
  int p = e0 >> 8, q = (e0 >> 7) & 1, d = e0 & 127;
  const float* src = x + ((long)((b_ * 56 + 2*i + p) * 56 + 2*j + q)) * 128 + d;
  float4 a  = *(const float4*)src;
  float4 b4 = *(const float4*)(src + 4);
  float vs[8] = {a.x, a.y, a.z, a.w, b4.x, b4.y, b4.z, b4.w};
  float s = 0.f, s2 = 0.f;
  #pragma unroll
  for (int u = 0; u < 8; u++) { s += vs[u]; s2 += vs[u] * vs[u]; }
  #pragma unroll
  for (int o = 32; o; o >>= 1) { s += __shfl_xor(s, o); s2 += __shfl_xor(s2, o); }
  float mean = s * (1.f / 512.f);
  float var  = s2 * (1.f / 512.f) - mean * mean;
  float rstd = rsqrtf(var + 1e-5f);
  u16 ov[8];
  #pragma unroll
  for (int u = 0; u < 8; u++) ov[u] = f2b((vs[u] - mean) * rstd * gw[e0+u] + bw[e0+u]);
  uint4 o4;
  o4.x = (u32)ov[0] | ((u32)ov[1] << 16);
  o4.y = (u32)ov[2] | ((u32)ov[3] << 16);
  o4.z = (u32)ov[4] | ((u32)ov[5] << 16);
  o4.w = (u32)ov[6] | ((u32)ov[7] << 16);
  *(uint4*)(dst + (long)t * 512 + e0) = o4;
}

// ---------------- MFMA window attention
// block = window (4096 blocks), wave = head. 16x16x32 bf16 MFMA, K=head_dim=32.
// S tile 64x64 (rows/cols >=49 masked), P via LDS, PV K=64 (2 k-steps).
template<int MASKED>
__global__ __launch_bounds__(256) void attn_mfma(const u16* __restrict__ qkv,
                                                 u16* __restrict__ obuf)
{
  __shared__ u16 Pls_all[4][64][72];   // 144B row stride: 16B-aligned, 2-way-free
  const int h = threadIdx.x >> 6;      // wave = head
  const int lane = threadIdx.x & 63;
  const int c = lane & 15, g = lane >> 4;
  const int wi = blockIdx.x;
  const int g_ = wi & 63;
  const long t0 = (long)wi * 49;
  u16 (*Pls)[72] = Pls_all[h];

  // ---- Q A-frags (4 m-tiles), K B-frags (4 n-tiles): direct 16B global loads
  bf16x8 qf[4], kf[4];
  #pragma unroll
  for (int mi = 0; mi < 4; mi++) {
    int r = 16*mi + c; r = r > 48 ? 48 : r;
    qf[mi] = *(const bf16x8*)(qkv + (t0 + r)*384 + h*32 + g*8);
  }
  #pragma unroll
  for (int ni = 0; ni < 4; ni++) {
    int r = 16*ni + c; r = r > 48 ? 48 : r;
    kf[ni] = *(const bf16x8*)(qkv + (t0 + r)*384 + 128 + h*32 + g*8);
  }

  // ---- S = Q K^T (16 MFMAs, single K-step)
  f32x4 acc[4][4];
  const f32x4 zero4 = {0.f, 0.f, 0.f, 0.f};
  #pragma unroll
  for (int mi = 0; mi < 4; mi++)
    #pragma unroll
    for (int ni = 0; ni < 4; ni++)
      acc[mi][ni] = __builtin_amdgcn_mfma_f32_16x16x32_bf16(qf[mi], kf[ni], zero4, 0, 0, 0);

  // ---- V B-frags for PV (issued early to hide latency): vf[ni2][ks]
  // lane holds V[k][n]: n = 16*ni2 + c, k = ks*32 + 8*g + jj
  bf16x8 vf[2][2];
  #pragma unroll
  for (int ni2 = 0; ni2 < 2; ni2++)
    #pragma unroll
    for (int ks = 0; ks < 2; ks++)
      #pragma unroll
      for (int jj = 0; jj < 8; jj++) {
        int k = ks*32 + 8*g + jj; k = k > 48 ? 48 : k;
        vf[ni2][ks][jj] = (short)qkv[(t0 + k)*384 + 256 + h*32 + 16*ni2 + c];
      }

  // ---- column region ids (shifted mask)
  int rid_c[4];
  int g1b = 0, g2b = 0;
  if (MASKED) {
    g1b = (g_ >> 3) * 7; g2b = (g_ & 7) * 7;
    #pragma unroll
    for (int ni = 0; ni < 4; ni++) {
      int col = 16*ni + c; col = col > 48 ? 48 : col;
      int cr = col / 7, cc = col - 7*cr;
      int hh = g1b + cr, ww = g2b + cc;
      rid_c[ni] = (hh < 49 ? 0 : (hh < 53 ? 1 : 2)) * 3 + (ww < 49 ? 0 : (ww < 53 ? 1 : 2));
    }
  }

  // ---- scale + mask + row softmax + P store (row r = 16mi+4g+j, col = 16ni+c)
  #pragma unroll
  for (int mi = 0; mi < 4; mi++) {
    #pragma unroll
    for (int j = 0; j < 4; j++) {
      int rr = 16*mi + 4*g + j;
      int rid_r = 0;
      if (MASKED) {
        int r2 = rr > 48 ? 48 : rr;
        int rh = r2 / 7, rw = r2 - 7*rh;
        int hh = g1b + rh, ww = g2b + rw;
        rid_r = (hh < 49 ? 0 : (hh < 53 ? 1 : 2)) * 3 + (ww < 49 ? 0 : (ww < 53 ? 1 : 2));
      }
      float sv[4];
      #pragma unroll
      for (int ni = 0; ni < 4; ni++) {
        float s = acc[mi][ni][j] * 0.17677669529663687f;   // 1/sqrt(32)
        int col = 16*ni + c;
        if (col >= 49) s = -1e30f;
        else if (MASKED && rid_c[ni] != rid_r) s -= 100.f;
        sv[ni] = s;
      }
      float m4 = fmaxf(fmaxf(sv[0], sv[1]), fmaxf(sv[2], sv[3]));
      #pragma unroll
      for (int o = 1; o <= 8; o <<= 1) m4 = fmaxf(m4, __shfl_xor(m4, o));
      float p[4], sum = 0.f;
      #pragma unroll
      for (int ni = 0; ni < 4; ni++) { p[ni] = __expf(sv[ni] - m4); sum += p[ni]; }
      #pragma unroll
      for (int o = 1; o <= 8; o <<= 1) sum += __shfl_xor(sum, o);
      float rs = 1.f / sum;
      #pragma unroll
      for (int ni = 0; ni < 4; ni++)
        Pls[rr][16*ni + c] = f2b(p[ni] * rs);
    }
  }

  __syncthreads();   // cheap safety: ensure P writes visible before frag reads

  // ---- O = P V  (A-frag row = 16mi+c, k = ks*32+g*8; 16 MFMAs)
  f32x4 accO[4][2];
  #pragma unroll
  for (int mi = 0; mi < 4; mi++)
    #pragma unroll
    for (int ni2 = 0; ni2 < 2; ni2++) accO[mi][ni2] = zero4;
  #pragma unroll
  for (int mi = 0; mi < 4; mi++)
    #pragma unroll
    for (int ks = 0; ks < 2; ks++) {
      bf16x8 pa = *(const bf16x8*)(&Pls[16*mi + c][ks*32 + g*8]);
      #pragma unroll
      for (int ni2 = 0; ni2 < 2; ni2++)
        accO[mi][ni2] = __builtin_amdgcn_mfma_f32_16x16x32_bf16(pa, vf[ni2][ks], accO[mi][ni2], 0, 0, 0);
    }

  // ---- store O rows < 49 (col = h*32 + 16*ni2 + c)
  #pragma unroll
  for (int mi = 0; mi < 4; mi++)
    #pragma unroll
    for (int ni2 = 0; ni2 < 2; ni2++)
      #pragma unroll
      for (int j = 0; j < 4; j++) {
        int r = 16*mi + 4*g + j;
        if (r < 49)
          obuf[(t0 + r)*128 + h*32 + 16*ni2 + c] = f2b(accO[mi][ni2][j]);
      }
}

// ---------------- MFMA GEMM: C[M,Ntot] = A[M,K](bf16) * Bt[Ntot,K]^T (bf16)
// 128x128 tile, 4 waves, BK=64, LDS pad +8 (conflict-free frag reads).
// EPI: 0 bias->bf16 | 1 bias+gelu->bf16 | 2 bias+residual f32 scatter (window->x)
//      3 bias, outf += (linear)         | 4 plain f32 store
template<int K, int EPI>
__global__ __launch_bounds__(256) void gemm_kernel(
    const u16* __restrict__ A, const u16* __restrict__ Bt,
    const float* __restrict__ bias, int Ntot,
    u16* __restrict__ outb, float* __restrict__ outf,
    const float* __restrict__ resbase, int shift)
{
  __shared__ u16 As[128][72];
  __shared__ u16 Bs[128][72];
  const int tid = threadIdx.x;
  const int row0 = blockIdx.x * 128, col0 = blockIdx.y * 128;
  const int wv = tid >> 6, lane = tid & 63;
  const int m_off = (wv >> 1) * 64, n_off = (wv & 1) * 64;
  const int lr = lane & 15, lk = (lane >> 4) * 8;

  f32x4 acc[4][4];
  const f32x4 zero4 = {0.f, 0.f, 0.f, 0.f};
  #pragma unroll
  for (int a1 = 0; a1 < 4; a1++)
    #pragma unroll
    for (int a2 = 0; a2 < 4; a2++) acc[a1][a2] = zero4;

  for (int k0 = 0; k0 < K; k0 += 64) {
    __syncthreads();
    #pragma unroll
    for (int j = 0; j < 4; j++) {
      int ch = tid + 256 * j;           // 1024 chunks of 16B
      int r = ch >> 3, cc = ch & 7;
      *(uint4*)(&As[r][cc*8]) = *(const uint4*)(A  + (long)(row0 + r) * K + k0 + cc*8);
      *(uint4*)(&Bs[r][cc*8]) = *(const uint4*)(Bt + (long)(col0 + r) * K + k0 + cc*8);
    }
    __syncthreads();
    #pragma unroll
    for (int kk = 0; kk < 64; kk += 32) {
      bf16x8 af[4], bfr[4];
      #pragma unroll
      for (int mi = 0; mi < 4; mi++)
        af[mi] = *(const bf16x8*)(&As[m_off + mi*16 + lr][kk + lk]);
      #pragma unroll
      for (int ni = 0; ni < 4; ni++)
        bfr[ni] = *(const bf16x8*)(&Bs[n_off + ni*16 + lr][kk + lk]);
      #pragma unroll
      for (int mi = 0; mi < 4; mi++)
        #pragma unroll
        for (int ni = 0; ni < 4; ni++)
          acc[mi][ni] = __builtin_amdgcn_mfma_f32_16x16x32_bf16(
              af[mi], bfr[ni], acc[mi][ni], 0, 0, 0);
    }
  }

  #pragma unroll
  for (int mi = 0; mi < 4; mi++) {
    #pragma unroll
    for (int j = 0; j < 4; j++) {
      int grow = row0 + m_off + mi*16 + (lane >> 4) * 4 + j;
      long obase = 0;
      if (EPI == 2) {
        int n = grow % 49; int tq = grow / 49; int gg = tq & 63; int b_ = tq >> 6;
        int r = n / 7, c = n - 7 * r;
        int hh = (gg >> 3) * 7 + r, ww = (gg & 7) * 7 + c;
        if (shift) { hh += 3; if (hh >= 56) hh -= 56; ww += 3; if (ww >= 56) ww -= 56; }
        obase = ((long)((b_ * 56 + hh) * 56 + ww)) * 128;
      }
      #pragma unroll
      for (int ni = 0; ni < 4; ni++) {
        int gcol = col0 + n_off + ni*16 + lr;
        float v = acc[mi][ni][j];
        if (EPI == 0) {
          v += bias[gcol];
          outb[(long)grow * Ntot + gcol] = f2b(v);
        } else if (EPI == 1) {
          v = gelu_tanh(v + bias[gcol]);
          outb[(long)grow * Ntot + gcol] = f2b(v);
        } else if (EPI == 2) {
          v += bias[gcol];
          outf[obase + gcol] = resbase[obase + gcol] + v;
        } else if (EPI == 3) {
          v += bias[gcol];
          outf[(long)grow * 128 + gcol] += v;
        } else {
          outf[(long)grow * Ntot + gcol] = v;
        }
      }
    }
  }
}

extern "C" void kernel_launch(void* const* d_in, const int* in_sizes, int n_in,
                              void* d_out, int out_size, void* d_ws, size_t ws_size,
                              hipStream_t stream)
{
  const float* x_in   = (const float*)d_in[0];
  const float* ln1_g  = (const float*)d_in[1];
  const float* ln1_b  = (const float*)d_in[2];
  const float* qkv_w  = (const float*)d_in[3];
  const float* qkv_b  = (const float*)d_in[4];
  const float* proj_w = (const float*)d_in[5];
  const float* proj_b = (const float*)d_in[6];
  const float* ln2_g  = (const float*)d_in[7];
  const float* ln2_b  = (const float*)d_in[8];
  const float* w1     = (const float*)d_in[9];
  const float* b1     = (const float*)d_in[10];
  const float* w2     = (const float*)d_in[11];
  const float* b2     = (const float*)d_in[12];
  const float* dsg    = (const float*)d_in[13];
  const float* dsb    = (const float*)d_in[14];
  const float* dsw    = (const float*)d_in[15];

  // workspace carve (~360 MB). buf_o aliases buf_h (never live simultaneously:
  // LN1 out (buf_h) is consumed by the QKV GEMM before attention writes buf_o).
  float* x_ws   = (float*)d_ws;                          // [MTOK][128] f32
  u16* buf_h    = (u16*)(x_ws + (long)MTOK * 128);       // [MTOK][128] bf16 (LN out / attn out / ds rows)
  u16* buf_o    = buf_h;                                 // alias
  u16* buf_big  = buf_h + (long)MTOK * 128;              // [MTOK][512] bf16 (qkv / mlp hidden)
  u16* wts      = buf_big + (long)MTOK * 512;
  u16* qkv_wt   = wts;                                   // [L][384][128]
  u16* proj_wt  = qkv_wt  + 2 * 49152;                   // [L][128][128]
  u16* w1t      = proj_wt + 2 * 16384;                   // [L][512][128]
  u16* w2t      = w1t     + 2 * 65536;                   // [L][128][512]
  u16* ds_wt    = w2t     + 2 * 65536;                   // [256][512]

  for (int i = 0; i < 2; i++) {
    transpose_cvt<<<(49152+255)/256, 256, 0, stream>>>(qkv_w  + i*49152, qkv_wt  + i*49152, 128, 384);
    transpose_cvt<<<(16384+255)/256, 256, 0, stream>>>(proj_w + i*16384, proj_wt + i*16384, 128, 128);
    transpose_cvt<<<(65536+255)/256, 256, 0, stream>>>(w1     + i*65536, w1t     + i*65536, 128, 512);
    transpose_cvt<<<(65536+255)/256, 256, 0, stream>>>(w2     + i*65536, w2t     + i*65536, 512, 128);
  }
  transpose_cvt<<<(131072+255)/256, 256, 0, stream>>>(dsw, ds_wt, 512, 256);

  for (int i = 0; i < 2; i++) {
    // LN1 (window order; layer1 = shifted gather)
    if (i == 0) ln_kernel<0><<<MTOK/4, 256, 0, stream>>>(x_in, ln1_g,       ln1_b,       buf_h);
    else        ln_kernel<1><<<MTOK/4, 256, 0, stream>>>(x_ws, ln1_g + 128, ln1_b + 128, buf_h);
    // QKV
    gemm_kernel<128,0><<<dim3(MTOK/128, 3), 256, 0, stream>>>(
        buf_h, qkv_wt + i*49152, qkv_b + i*384, 384, buf_big, nullptr, nullptr, 0);
    // attention (MFMA)
    if (i == 0) attn_mfma<0><<<4096, 256, 0, stream>>>(buf_big, buf_o);
    else        attn_mfma<1><<<4096, 256, 0, stream>>>(buf_big, buf_o);
    // proj + residual scatter into x_ws
    gemm_kernel<128,2><<<dim3(MTOK/128, 1), 256, 0, stream>>>(
        buf_o, proj_wt + i*16384, proj_b + i*128, 128, nullptr, x_ws,
        (i == 0 ? x_in : (const float*)x_ws), i);
    // LN2 (linear)
    ln_kernel<2><<<MTOK/4, 256, 0, stream>>>(x_ws, ln2_g + i*128, ln2_b + i*128, buf_h);
    // MLP
    gemm_kernel<128,1><<<dim3(MTOK/128, 4), 256, 0, stream>>>(
        buf_h, w1t + i*65536, b1 + i*512, 512, buf_big, nullptr, nullptr, 0);
    gemm_kernel<512,3><<<dim3(MTOK/128, 1), 256, 0, stream>>>(
        buf_big, w2t + i*65536, b2 + i*128, 128, nullptr, x_ws, x_ws, 0);
  }

  // downsample
  ds_ln_kernel<<<DSTOK/4, 256, 0, stream>>>(x_ws, dsg, dsb, buf_h);
  gemm_kernel<512,4><<<dim3(DSTOK/128, 2), 256, 0, stream>>>(
      buf_h, ds_wt, nullptr, 256, nullptr, (float*)d_out, nullptr, 0);
}